// Round 9
// baseline (404.379 us; speedup 1.0000x reference)
//
#include <hip/hip_runtime.h>

typedef _Float16 f16;
typedef __fp16 fp16x2 __attribute__((ext_vector_type(2)));
typedef _Float16 f16x8 __attribute__((ext_vector_type(8)));
typedef float f32x4 __attribute__((ext_vector_type(4)));
typedef int i32x4 __attribute__((ext_vector_type(4)));

#define T_TOK 2048
#define HD 3584
#define NQH 28
#define NKVH 4
#define QKVN 4608
#define OROW 3584
#define SOFTMAX_SCALE 0.088388347648318447f

// ---------------- fused fp32 -> fp16 convert for TWO arrays ------------------
__global__ __launch_bounds__(256) void cvt2_kernel(const float* __restrict__ src1,
                                                   f16* __restrict__ dst1, int n1,
                                                   const float* __restrict__ src2,
                                                   f16* __restrict__ dst2, int n2) {
  int nb1 = n1 / 2048;
  const float* src;
  f16* dst;
  int i;
  if (blockIdx.x < (unsigned)nb1) {
    src = src1; dst = dst1;
    i = (blockIdx.x * 256 + threadIdx.x) * 8;
    if (i >= n1) return;
  } else {
    src = src2; dst = dst2;
    i = ((blockIdx.x - nb1) * 256 + threadIdx.x) * 8;
    if (i >= n2) return;
  }
  f32x4 a = *(const f32x4*)(src + i);
  f32x4 b = *(const f32x4*)(src + i + 4);
  f16x8 o;
  o[0] = (f16)a[0]; o[1] = (f16)a[1]; o[2] = (f16)a[2]; o[3] = (f16)a[3];
  o[4] = (f16)b[0]; o[5] = (f16)b[1]; o[6] = (f16)b[2]; o[7] = (f16)b[3];
  *(f16x8*)(dst + i) = o;
}

// ---------------- GEMM (LDS path, f16 A/W): R3/R5/R8 proven, 101us QKV -------
template <typename OutT, bool HAS_BIAS, int BN>
__global__ __launch_bounds__(256) void gemm_lds(const f16* __restrict__ A,
                                                const f16* __restrict__ W,
                                                const float* __restrict__ scale,
                                                const float* __restrict__ bias,
                                                OutT* __restrict__ C,
                                                int M, int N, int K) {
  constexpr int WN = BN / 2;
  constexpr int NF = WN / 16;
  constexpr int WCH = BN / 16;
  __shared__ alignas(16) f16 As[3][128 * 32];
  __shared__ alignas(16) f16 Ws[3][BN * 32];
  const int tid = threadIdx.x;
  const int lane = tid & 63;
  const int wid = tid >> 6;
  const int wm = wid >> 1, wn = wid & 1;
  const int bm = blockIdx.y * 128, bn = blockIdx.x * BN;

  const int fr = lane & 15;
  const int hi = lane >> 4;
  const int sw = (hi ^ ((fr >> 1) & 3)) * 8;

  const int c0 = wid, c1 = wid + 4;
  const int srow = lane >> 2;
  const int scol = ((lane & 3) ^ ((srow >> 1) & 3)) * 8;
  const f16* ga0 = A + (size_t)(bm + c0 * 16 + srow) * K + scol;
  const f16* ga1 = A + (size_t)(bm + c1 * 16 + srow) * K + scol;
  const f16* gw0 = W + (size_t)(bn + c0 * 16 + srow) * K + scol;
  const f16* gw1 = W + (size_t)(bn + c1 * 16 + srow) * K + scol;

  auto STAGE = [&](int buf, int s) {
    const int k0 = s << 5;
    __builtin_amdgcn_global_load_lds(
        (const __attribute__((address_space(1))) void*)(ga0 + k0),
        (__attribute__((address_space(3))) void*)(As[buf] + c0 * 512), 16, 0, 0);
    __builtin_amdgcn_global_load_lds(
        (const __attribute__((address_space(1))) void*)(ga1 + k0),
        (__attribute__((address_space(3))) void*)(As[buf] + c1 * 512), 16, 0, 0);
    __builtin_amdgcn_global_load_lds(
        (const __attribute__((address_space(1))) void*)(gw0 + k0),
        (__attribute__((address_space(3))) void*)(Ws[buf] + c0 * 512), 16, 0, 0);
    if (c1 < WCH)
      __builtin_amdgcn_global_load_lds(
          (const __attribute__((address_space(1))) void*)(gw1 + k0),
          (__attribute__((address_space(3))) void*)(Ws[buf] + c1 * 512), 16, 0, 0);
  };

  f32x4 acc[4][NF] = {};
  f16x8 af0[4], wf0[NF], af1[4], wf1[NF];

  auto LOADF = [&](f16x8* af, f16x8* wf, int b) {
#pragma unroll
    for (int i = 0; i < 4; ++i)
      af[i] = *(const f16x8*)(As[b] + (wm * 64 + i * 16 + fr) * 32 + sw);
#pragma unroll
    for (int i = 0; i < NF; ++i)
      wf[i] = *(const f16x8*)(Ws[b] + (wn * WN + i * 16 + fr) * 32 + sw);
  };
  auto MM = [&](const f16x8* af, const f16x8* wf) {
#pragma unroll
    for (int mi = 0; mi < 4; ++mi)
#pragma unroll
      for (int ni = 0; ni < NF; ++ni)
        acc[mi][ni] = __builtin_amdgcn_mfma_f32_16x16x32_f16(af[mi], wf[ni], acc[mi][ni], 0, 0, 0);
  };

  const int nsteps = K >> 5;  // 112 (even)
  STAGE(0, 0);
  STAGE(1, 1);
  __syncthreads();
  LOADF(af0, wf0, 0);

  int bA = 0;
  for (int s = 0; s < nsteps; s += 2) {
    int bB = bA + 1; if (bB >= 3) bB -= 3;
    int bC = bB + 1; if (bC >= 3) bC -= 3;

    if (s + 2 < nsteps) STAGE(bC, s + 2);
    LOADF(af1, wf1, bB);
    MM(af0, wf0);
    __syncthreads();

    if (s + 3 < nsteps) STAGE(bA, s + 3);
    if (s + 2 < nsteps) LOADF(af0, wf0, bC);
    MM(af1, wf1);
    __syncthreads();

    bA = bC;
  }

  const int rb = (lane >> 4) * 4;
#pragma unroll
  for (int ni = 0; ni < NF; ++ni) {
    int c = bn + wn * WN + ni * 16 + fr;
    float sc = scale[c];
    float bi = HAS_BIAS ? bias[c] : 0.0f;
#pragma unroll
    for (int mi = 0; mi < 4; ++mi) {
#pragma unroll
      for (int j = 0; j < 4; ++j) {
        int r = bm + wm * 64 + mi * 16 + rb + j;
        float v = acc[mi][ni][j] * sc + bi;
        C[(size_t)r * N + c] = (OutT)v;
      }
    }
  }
}

// ---------------- GEMM (fused-W path): R4/R5 proven, O GEMM only -------------
template <typename OutT, bool HAS_BIAS, int BN>
__global__ __launch_bounds__(256, 4) void gemm_fw(const f16* __restrict__ A,
                                                  const float* __restrict__ W,
                                                  const float* __restrict__ scale,
                                                  const float* __restrict__ bias,
                                                  OutT* __restrict__ C,
                                                  int M, int N, int K) {
  constexpr int WN = BN / 2;
  constexpr int NF = WN / 16;
  constexpr int WCH = BN / 16;
  __shared__ alignas(16) f16 As[3][128 * 32];
  __shared__ alignas(16) f16 Ws[3][BN * 32];
  const int tid = threadIdx.x;
  const int lane = tid & 63;
  const int wid = tid >> 6;
  const int wm = wid >> 1, wn = wid & 1;
  const int bm = blockIdx.y * 128, bn = blockIdx.x * BN;

  const int fr = lane & 15;
  const int hi = lane >> 4;
  const int sw = (hi ^ ((fr >> 1) & 3)) * 8;

  const int c0 = wid, c1 = wid + 4;
  const int srow = lane >> 2;
  const int l4 = lane & 3;
  const int dcol = (l4 ^ ((srow >> 1) & 3)) * 8;
  const bool hasW1 = (c1 < WCH);

  const size_t arow0 = (size_t)(bm + c0 * 16 + srow) * K + l4 * 8;
  const size_t arow1 = (size_t)(bm + c1 * 16 + srow) * K + l4 * 8;
  const size_t wrow0 = (size_t)(bn + c0 * 16 + srow) * K + l4 * 8;
  const size_t wrow1 = (size_t)(bn + c1 * 16 + srow) * K + l4 * 8;

  f16x8 sa16[2];
  f32x4 swr[4];

  auto ISSUE = [&](int s) {
    const int kf = s << 5;
    sa16[0] = *(const f16x8*)(A + arow0 + kf);
    sa16[1] = *(const f16x8*)(A + arow1 + kf);
    const float* q0 = W + wrow0 + kf;
    swr[0] = *(const f32x4*)q0;
    swr[1] = *(const f32x4*)(q0 + 4);
    if (hasW1) {
      const float* q1 = W + wrow1 + kf;
      swr[2] = *(const f32x4*)q1;
      swr[3] = *(const f32x4*)(q1 + 4);
    }
  };

  auto CVT = [](f32x4 lo, f32x4 hiv) {
    f16x8 o;
    o[0] = (f16)lo[0]; o[1] = (f16)lo[1]; o[2] = (f16)lo[2]; o[3] = (f16)lo[3];
    o[4] = (f16)hiv[0]; o[5] = (f16)hiv[1]; o[6] = (f16)hiv[2]; o[7] = (f16)hiv[3];
    return o;
  };

  auto WRITE = [&](int buf) {
    *(f16x8*)(As[buf] + c0 * 512 + srow * 32 + dcol) = sa16[0];
    *(f16x8*)(As[buf] + c1 * 512 + srow * 32 + dcol) = sa16[1];
    *(f16x8*)(Ws[buf] + c0 * 512 + srow * 32 + dcol) = CVT(swr[0], swr[1]);
    if (hasW1)
      *(f16x8*)(Ws[buf] + c1 * 512 + srow * 32 + dcol) = CVT(swr[2], swr[3]);
  };

  f32x4 acc[4][NF] = {};

  const int nsteps = K >> 5;
  ISSUE(0);
  WRITE(0);
  ISSUE(1);

  int cur = 0;
  for (int s = 0; s < nsteps; ++s) {
    int nb = cur + 1;
    if (nb >= 3) nb -= 3;
    if (s + 1 < nsteps) WRITE(nb);
    if (s + 2 < nsteps) ISSUE(s + 2);
    asm volatile("s_waitcnt lgkmcnt(0)" ::: "memory");
    __builtin_amdgcn_s_barrier();
    asm volatile("" ::: "memory");

    f16x8 af[4], wf[NF];
#pragma unroll
    for (int i = 0; i < 4; ++i)
      af[i] = *(const f16x8*)(As[cur] + (wm * 64 + i * 16 + fr) * 32 + sw);
#pragma unroll
    for (int i = 0; i < NF; ++i)
      wf[i] = *(const f16x8*)(Ws[cur] + (wn * WN + i * 16 + fr) * 32 + sw);
#pragma unroll
    for (int mi = 0; mi < 4; ++mi)
#pragma unroll
      for (int ni = 0; ni < NF; ++ni)
        acc[mi][ni] = __builtin_amdgcn_mfma_f32_16x16x32_f16(af[mi], wf[ni], acc[mi][ni], 0, 0, 0);

    cur = nb;
  }

  const int rb = (lane >> 4) * 4;
#pragma unroll
  for (int ni = 0; ni < NF; ++ni) {
    int c = bn + wn * WN + ni * 16 + fr;
    float sc = scale[c];
    float bi = HAS_BIAS ? bias[c] : 0.0f;
#pragma unroll
    for (int mi = 0; mi < 4; ++mi) {
#pragma unroll
      for (int j = 0; j < 4; ++j) {
        int r = bm + wm * 64 + mi * 16 + rb + j;
        float v = acc[mi][ni][j] * sc + bi;
        C[(size_t)r * N + c] = (OutT)v;
      }
    }
  }
}

// ---------------- fused RoPE + V-transpose (one dispatch, R8 proven) ---------
__global__ __launch_bounds__(256) void rope_vt_kernel(const int* __restrict__ positions,
                                                      const f16* __restrict__ qkv,
                                                      f16* __restrict__ qkv_r,
                                                      f16* __restrict__ vt) {
  const int bid = blockIdx.x;
  if (bid < T_TOK) {
    int t = bid;
    float pos = (float)positions[t];
    const f16* in = qkv + (size_t)t * QKVN;
    f16* out = qkv_r + (size_t)t * QKVN;
#pragma unroll
    for (int it = 0; it < 8; ++it) {
      int item = it * 256 + threadIdx.x;
      int head = item >> 6;
      int j = item & 63;
      int col = (head < NQH) ? head * 128 : 3584 + (head - NQH) * 128;
      float freq = pos * exp2f(-(float)j * (19.931568569324174f / 64.0f));
      float s, c;
      sincosf(freq, &s, &c);
      float x1 = (float)in[col + j];
      float x2 = (float)in[col + j + 64];
      out[col + j] = (f16)(x1 * c - x2 * s);
      out[col + j + 64] = (f16)(x2 * c + x1 * s);
    }
  } else {
    int v = bid - T_TOK;
    int kv = v >> 6;
    int t0 = (v & 63) * 32;
    __shared__ f16 buf[32][136];
    const f16* src = qkv + 4096 + kv * 128;
#pragma unroll
    for (int it = 0; it < 16; ++it) {
      int e = it * 256 + threadIdx.x;
      int tt = e >> 7, d = e & 127;
      buf[tt][d] = src[(size_t)(t0 + tt) * QKVN + d];
    }
    __syncthreads();
#pragma unroll
    for (int it = 0; it < 16; ++it) {
      int e = it * 256 + threadIdx.x;
      int d = e >> 5, tt = e & 31;
      vt[((size_t)kv * 128 + d) * T_TOK + t0 + tt] = buf[tt][d];
    }
  }
}

// ---------------- Flash attention v9: V direct-from-global (no Vs) -----------
// R8 analysis: attn is DS-pipe-bound (~576 DS-cyc/wave-tile vs ~154 MFMA).
// v9 removes V from LDS entirely: the staged-swizzled round trip provably
// equals vf = V[d=nd*16+fr][s0+(4c+hi)*8+e] (XOR cancels: write col
// (vc^(d&7))*8 of data t=vc*8; read col ((4c+hi)^(fr&7))*8 with d&7==fr&7).
// vfr0 (c=0 batch) issues at tile start (QK covers latency); vfr1 (c=1) right
// after QK (softmax covers). V working set 512KB/kv-head is L2-resident
// (shared by 112 blocks; 4x read amp = ~14 TB/s L2, 40% of ceiling).
// DS/tile: 16 kf reads + 4 K ds_writes + bpermutes = ~340 cyc (-40%).
// K path, QK, softmax, PV math byte-identical to the verified v8.
__global__ __launch_bounds__(256, 2) void attn_kernel(const f16* __restrict__ qkv_r,
                                                      const f16* __restrict__ vt,
                                                      f16* __restrict__ o) {
  __shared__ alignas(16) f16 Ks[2][8192];
  const int h = blockIdx.y;
  const int kv = h / 7;
  const int bq = blockIdx.x;               // 0..15
  const int tt = threadIdx.x;
  const int w = tt >> 6;
  const int lane = tt & 63;
  const int qa = 64 * bq + 16 * w;
  const int qb = 1984 - 64 * bq + 16 * w;
  const int fr = lane & 15;
  const int hi = lane >> 4;
  const int fk = hi * 8;
  const int rb = hi * 4;
  const int ntiles = 32 - bq;

  const f16* kgbase = qkv_r + 3584 + kv * 128;
  const f16* vgbase = vt + (size_t)kv * 128 * T_TOK;

  const int krow0 = tt >> 4, kc = tt & 15;
  const int kds = (kc ^ (krow0 & 7)) * 8;

  f16x8 qf[2][4];
#pragma unroll
  for (int fa = 0; fa < 2; ++fa) {
    const f16* qp = qkv_r + (size_t)((fa ? qb : qa) + fr) * QKVN + h * 128 + fk;
#pragma unroll
    for (int f = 0; f < 4; ++f) qf[fa][f] = *(const f16x8*)(qp + f * 32);
  }

  f32x4 oacc[2][8] = {};
  float m[2] = {-3.0e38f, -3.0e38f};
  float l[2] = {0.0f, 0.0f};

#pragma unroll
  for (int i = 0; i < 4; ++i) {
    f16x8 kx = *(const f16x8*)(kgbase + (size_t)(krow0 + 16 * i) * QKVN + kc * 8);
    *(f16x8*)&Ks[0][(krow0 + 16 * i) * 128 + kds] = kx;
  }
  __syncthreads();

  for (int tile = 0; tile < ntiles; ++tile) {
    const int s0 = tile << 6;
    const int cur = tile & 1;
    const bool havestage = (tile + 1 < ntiles);

    f16x8 sk[4];
    if (havestage) {
      const int s1 = s0 + 64;
#pragma unroll
      for (int i = 0; i < 4; ++i)
        sk[i] = *(const f16x8*)(kgbase + (size_t)(s1 + krow0 + 16 * i) * QKVN + kc * 8);
    }

    // V c=0 fragment batch for THIS tile, direct from global (L2-hot).
    f16x8 vfr0[8];
#pragma unroll
    for (int nd = 0; nd < 8; ++nd)
      vfr0[nd] = *(const f16x8*)(vgbase + (size_t)(nd * 16 + fr) * T_TOK + s0 + hi * 8);

    {
      const f16* Kc = Ks[cur];
      const bool actA = s0 < qa + 16;

      f32x4 sacc[2][4] = {};
      __builtin_amdgcn_s_setprio(1);
      if (actA) {
#pragma unroll
        for (int jj = 0; jj < 4; ++jj) {
          const int krow = jj * 16 + fr;
#pragma unroll
          for (int f = 0; f < 4; ++f) {
            f16x8 kf = *(const f16x8*)&Kc[krow * 128 + (((4 * f + hi) ^ (fr & 7)) * 8)];
            sacc[1][jj] = __builtin_amdgcn_mfma_f32_16x16x32_f16(kf, qf[1][f], sacc[1][jj], 0, 0, 0);
            sacc[0][jj] = __builtin_amdgcn_mfma_f32_16x16x32_f16(kf, qf[0][f], sacc[0][jj], 0, 0, 0);
          }
        }
      } else {
#pragma unroll
        for (int jj = 0; jj < 4; ++jj) {
          const int krow = jj * 16 + fr;
#pragma unroll
          for (int f = 0; f < 4; ++f) {
            f16x8 kf = *(const f16x8*)&Kc[krow * 128 + (((4 * f + hi) ^ (fr & 7)) * 8)];
            sacc[1][jj] = __builtin_amdgcn_mfma_f32_16x16x32_f16(kf, qf[1][f], sacc[1][jj], 0, 0, 0);
          }
        }
      }
      __builtin_amdgcn_s_setprio(0);

      // V c=1 batch: issued here so softmax covers its latency.
      f16x8 vfr1[8];
#pragma unroll
      for (int nd = 0; nd < 8; ++nd)
        vfr1[nd] = *(const f16x8*)(vgbase + (size_t)(nd * 16 + fr) * T_TOK + s0 + 32 + hi * 8);

      int pw[2][2][4];
#pragma unroll
      for (int fa = 0; fa < 2; ++fa) {
        if (fa == 0 && !actA) continue;
        const int qrow = (fa ? qb : qa) + fr;
        float p[4][4];
#pragma unroll
        for (int jj = 0; jj < 4; ++jj)
#pragma unroll
          for (int jv = 0; jv < 4; ++jv) {
            int kvi = s0 + jj * 16 + rb + jv;
            float sv2 = sacc[fa][jj][jv] * SOFTMAX_SCALE;
            p[jj][jv] = (kvi <= qrow) ? sv2 : -3.0e38f;
          }
        float vmax = -3.0e38f;
#pragma unroll
        for (int jj = 0; jj < 4; ++jj)
          vmax = fmaxf(vmax, fmaxf(fmaxf(p[jj][0], p[jj][1]), fmaxf(p[jj][2], p[jj][3])));
        vmax = fmaxf(vmax, __shfl_xor(vmax, 16));
        vmax = fmaxf(vmax, __shfl_xor(vmax, 32));
        if (!__all(vmax <= m[fa] + 8.0f)) {
          float mn = fmaxf(m[fa], vmax);
          float corr = __expf(m[fa] - mn);
          m[fa] = mn;
          l[fa] *= corr;
#pragma unroll
          for (int jv = 0; jv < 4; ++jv) {
            float cj = __shfl(corr, rb + jv);
#pragma unroll
            for (int nd = 0; nd < 8; ++nd) oacc[fa][nd][jv] *= cj;
          }
        }
        float rs = 0.0f;
#pragma unroll
        for (int jj = 0; jj < 4; ++jj)
#pragma unroll
          for (int jv = 0; jv < 4; ++jv) {
            p[jj][jv] = __expf(p[jj][jv] - m[fa]);
            rs += p[jj][jv];
          }
        rs += __shfl_xor(rs, 16);
        rs += __shfl_xor(rs, 32);
        l[fa] += rs;

        int wp[4][2];
#pragma unroll
        for (int jj = 0; jj < 4; ++jj)
#pragma unroll
          for (int u = 0; u < 2; ++u) {
            fp16x2 h2 = __builtin_amdgcn_cvt_pkrtz(p[jj][2 * u], p[jj][2 * u + 1]);
            wp[jj][u] = __builtin_bit_cast(int, h2);
          }
#pragma unroll
        for (int c = 0; c < 2; ++c)
#pragma unroll
          for (int t = 0; t < 4; ++t) {
            int src = fr + 16 * (2 * (hi & 1) + (t >> 1));
            int a0 = __shfl(wp[2 * c][t & 1], src);
            int b0 = __shfl(wp[2 * c + 1][t & 1], src);
            pw[fa][c][t] = (hi >> 1) ? b0 : a0;
          }
      }

      __builtin_amdgcn_s_setprio(1);
#pragma unroll
      for (int c = 0; c < 2; ++c) {
        i32x4 t1 = {pw[1][c][0], pw[1][c][1], pw[1][c][2], pw[1][c][3]};
        f16x8 pf1 = __builtin_bit_cast(f16x8, t1);
        if (actA) {
          i32x4 t0 = {pw[0][c][0], pw[0][c][1], pw[0][c][2], pw[0][c][3]};
          f16x8 pf0 = __builtin_bit_cast(f16x8, t0);
#pragma unroll
          for (int nd = 0; nd < 8; ++nd) {
            f16x8 vf = (c == 0) ? vfr0[nd] : vfr1[nd];
            oacc[1][nd] = __builtin_amdgcn_mfma_f32_16x16x32_f16(pf1, vf, oacc[1][nd], 0, 0, 0);
            oacc[0][nd] = __builtin_amdgcn_mfma_f32_16x16x32_f16(pf0, vf, oacc[0][nd], 0, 0, 0);
          }
        } else {
#pragma unroll
          for (int nd = 0; nd < 8; ++nd) {
            f16x8 vf = (c == 0) ? vfr0[nd] : vfr1[nd];
            oacc[1][nd] = __builtin_amdgcn_mfma_f32_16x16x32_f16(pf1, vf, oacc[1][nd], 0, 0, 0);
          }
        }
      }
      __builtin_amdgcn_s_setprio(0);
    }

    if (havestage) {
      const int nxt = cur ^ 1;
#pragma unroll
      for (int i = 0; i < 4; ++i)
        *(f16x8*)&Ks[nxt][(krow0 + 16 * i) * 128 + kds] = sk[i];
      __syncthreads();
    }
  }

#pragma unroll
  for (int fa = 0; fa < 2; ++fa) {
    float inv[4];
#pragma unroll
    for (int jv = 0; jv < 4; ++jv) inv[jv] = 1.0f / __shfl(l[fa], rb + jv);
    f16* ob = o + (size_t)(fa ? qb : qa) * OROW + h * 128;
#pragma unroll
    for (int nd = 0; nd < 8; ++nd)
#pragma unroll
      for (int jv = 0; jv < 4; ++jv)
        ob[(size_t)(rb + jv) * OROW + nd * 16 + fr] = (f16)(oacc[fa][nd][jv] * inv[jv]);
  }
}

extern "C" void kernel_launch(void* const* d_in, const int* in_sizes, int n_in,
                              void* d_out, int out_size, void* d_ws, size_t ws_size,
                              hipStream_t stream) {
  (void)in_sizes; (void)n_in; (void)out_size; (void)ws_size;
  const int* positions = (const int*)d_in[0];
  const float* hidden = (const float*)d_in[1];
  const float* qkv_w = (const float*)d_in[2];
  const float* qkv_scale = (const float*)d_in[3];
  const float* qkv_bias = (const float*)d_in[4];
  const float* o_w = (const float*)d_in[5];
  const float* o_scale = (const float*)d_in[6];
  float* out = (float*)d_out;

  char* ws = (char*)d_ws;
  size_t off = 0;
  auto alloc = [&](size_t bytes) {
    char* p = ws + off;
    off += (bytes + 255) & ~(size_t)255;
    return p;
  };
  f16* bufA = (f16*)alloc((size_t)T_TOK * HD * 2);   // hidden f16, later attn out
  f16* bufB = (f16*)alloc((size_t)QKVN * HD * 2);    // qkv_w f16
  f16* qkv_h = (f16*)alloc((size_t)T_TOK * QKVN * 2);
  f16* qkv_r = (f16*)alloc((size_t)T_TOK * QKVN * 2);
  f16* vtb = (f16*)alloc((size_t)NKVH * 128 * T_TOK * 2);

  // one dispatch: hidden + qkv_w f32->f16
  const int n1 = T_TOK * HD, n2 = QKVN * HD;
  cvt2_kernel<<<(n1 + n2) / 2048, 256, 0, stream>>>(hidden, bufA, n1, qkv_w, bufB, n2);

  // QKV GEMM: proven gload_lds path, 96-col tiles -> 768 blocks = 3.0/CU
  gemm_lds<f16, true, 96><<<dim3(QKVN / 96, T_TOK / 128), 256, 0, stream>>>(
      bufA, bufB, qkv_scale, qkv_bias, qkv_h, T_TOK, QKVN, HD);

  // one dispatch: rope (blocks 0..2047) + V-transpose (blocks 2048..2303)
  rope_vt_kernel<<<T_TOK + (T_TOK / 32) * NKVH, 256, 0, stream>>>(
      positions, qkv_h, qkv_r, vtb);

  attn_kernel<<<dim3(16, NQH), 256, 0, stream>>>(qkv_r, vtb, bufA);

  // O GEMM: fused-W reg-staging (R4/R5 winner): A = attn out f16, W = o_w f32.
  gemm_fw<float, false, 128><<<dim3(OROW / 128, T_TOK / 128), 256, 0, stream>>>(
      bufA, o_w, o_scale, nullptr, out, T_TOK, OROW, HD);
}

// Round 10
// 260.806 us; speedup vs baseline: 1.5505x; 1.5505x over previous
//
#include <hip/hip_runtime.h>

typedef _Float16 f16;
typedef __fp16 fp16x2 __attribute__((ext_vector_type(2)));
typedef _Float16 f16x8 __attribute__((ext_vector_type(8)));
typedef float f32x4 __attribute__((ext_vector_type(4)));
typedef int i32x4 __attribute__((ext_vector_type(4)));

#define T_TOK 2048
#define HD 3584
#define NQH 28
#define NKVH 4
#define QKVN 4608
#define OROW 3584
#define SOFTMAX_SCALE 0.088388347648318447f

// ---------------- fused fp32 -> fp16 convert for TWO arrays ------------------
__global__ __launch_bounds__(256) void cvt2_kernel(const float* __restrict__ src1,
                                                   f16* __restrict__ dst1, int n1,
                                                   const float* __restrict__ src2,
                                                   f16* __restrict__ dst2, int n2) {
  int nb1 = n1 / 2048;
  const float* src;
  f16* dst;
  int i;
  if (blockIdx.x < (unsigned)nb1) {
    src = src1; dst = dst1;
    i = (blockIdx.x * 256 + threadIdx.x) * 8;
    if (i >= n1) return;
  } else {
    src = src2; dst = dst2;
    i = ((blockIdx.x - nb1) * 256 + threadIdx.x) * 8;
    if (i >= n2) return;
  }
  f32x4 a = *(const f32x4*)(src + i);
  f32x4 b = *(const f32x4*)(src + i + 4);
  f16x8 o;
  o[0] = (f16)a[0]; o[1] = (f16)a[1]; o[2] = (f16)a[2]; o[3] = (f16)a[3];
  o[4] = (f16)b[0]; o[5] = (f16)b[1]; o[6] = (f16)b[2]; o[7] = (f16)b[3];
  *(f16x8*)(dst + i) = o;
}

// ---------------- GEMM (LDS path, f16 A/W): R3/R5/R8 proven, 101us QKV -------
// At the documented 2-phase structural ceiling (~673 TF); counted-vmcnt /
// conflict-free swizzle / cross-step reg pipeline all proven neutral here.
template <typename OutT, bool HAS_BIAS, int BN>
__global__ __launch_bounds__(256) void gemm_lds(const f16* __restrict__ A,
                                                const f16* __restrict__ W,
                                                const float* __restrict__ scale,
                                                const float* __restrict__ bias,
                                                OutT* __restrict__ C,
                                                int M, int N, int K) {
  constexpr int WN = BN / 2;
  constexpr int NF = WN / 16;
  constexpr int WCH = BN / 16;
  __shared__ alignas(16) f16 As[3][128 * 32];
  __shared__ alignas(16) f16 Ws[3][BN * 32];
  const int tid = threadIdx.x;
  const int lane = tid & 63;
  const int wid = tid >> 6;
  const int wm = wid >> 1, wn = wid & 1;
  const int bm = blockIdx.y * 128, bn = blockIdx.x * BN;

  const int fr = lane & 15;
  const int hi = lane >> 4;
  const int sw = (hi ^ ((fr >> 1) & 3)) * 8;

  const int c0 = wid, c1 = wid + 4;
  const int srow = lane >> 2;
  const int scol = ((lane & 3) ^ ((srow >> 1) & 3)) * 8;
  const f16* ga0 = A + (size_t)(bm + c0 * 16 + srow) * K + scol;
  const f16* ga1 = A + (size_t)(bm + c1 * 16 + srow) * K + scol;
  const f16* gw0 = W + (size_t)(bn + c0 * 16 + srow) * K + scol;
  const f16* gw1 = W + (size_t)(bn + c1 * 16 + srow) * K + scol;

  auto STAGE = [&](int buf, int s) {
    const int k0 = s << 5;
    __builtin_amdgcn_global_load_lds(
        (const __attribute__((address_space(1))) void*)(ga0 + k0),
        (__attribute__((address_space(3))) void*)(As[buf] + c0 * 512), 16, 0, 0);
    __builtin_amdgcn_global_load_lds(
        (const __attribute__((address_space(1))) void*)(ga1 + k0),
        (__attribute__((address_space(3))) void*)(As[buf] + c1 * 512), 16, 0, 0);
    __builtin_amdgcn_global_load_lds(
        (const __attribute__((address_space(1))) void*)(gw0 + k0),
        (__attribute__((address_space(3))) void*)(Ws[buf] + c0 * 512), 16, 0, 0);
    if (c1 < WCH)
      __builtin_amdgcn_global_load_lds(
          (const __attribute__((address_space(1))) void*)(gw1 + k0),
          (__attribute__((address_space(3))) void*)(Ws[buf] + c1 * 512), 16, 0, 0);
  };

  f32x4 acc[4][NF] = {};
  f16x8 af0[4], wf0[NF], af1[4], wf1[NF];

  auto LOADF = [&](f16x8* af, f16x8* wf, int b) {
#pragma unroll
    for (int i = 0; i < 4; ++i)
      af[i] = *(const f16x8*)(As[b] + (wm * 64 + i * 16 + fr) * 32 + sw);
#pragma unroll
    for (int i = 0; i < NF; ++i)
      wf[i] = *(const f16x8*)(Ws[b] + (wn * WN + i * 16 + fr) * 32 + sw);
  };
  auto MM = [&](const f16x8* af, const f16x8* wf) {
#pragma unroll
    for (int mi = 0; mi < 4; ++mi)
#pragma unroll
      for (int ni = 0; ni < NF; ++ni)
        acc[mi][ni] = __builtin_amdgcn_mfma_f32_16x16x32_f16(af[mi], wf[ni], acc[mi][ni], 0, 0, 0);
  };

  const int nsteps = K >> 5;  // 112 (even)
  STAGE(0, 0);
  STAGE(1, 1);
  __syncthreads();
  LOADF(af0, wf0, 0);

  int bA = 0;
  for (int s = 0; s < nsteps; s += 2) {
    int bB = bA + 1; if (bB >= 3) bB -= 3;
    int bC = bB + 1; if (bC >= 3) bC -= 3;

    if (s + 2 < nsteps) STAGE(bC, s + 2);
    LOADF(af1, wf1, bB);
    MM(af0, wf0);
    __syncthreads();

    if (s + 3 < nsteps) STAGE(bA, s + 3);
    if (s + 2 < nsteps) LOADF(af0, wf0, bC);
    MM(af1, wf1);
    __syncthreads();

    bA = bC;
  }

  const int rb = (lane >> 4) * 4;
#pragma unroll
  for (int ni = 0; ni < NF; ++ni) {
    int c = bn + wn * WN + ni * 16 + fr;
    float sc = scale[c];
    float bi = HAS_BIAS ? bias[c] : 0.0f;
#pragma unroll
    for (int mi = 0; mi < 4; ++mi) {
#pragma unroll
      for (int j = 0; j < 4; ++j) {
        int r = bm + wm * 64 + mi * 16 + rb + j;
        float v = acc[mi][ni][j] * sc + bi;
        C[(size_t)r * N + c] = (OutT)v;
      }
    }
  }
}

// ---------------- GEMM (fused-W path): R4/R5 proven, O GEMM only -------------
// Measured win on O (1.75 blk/CU latency headroom); measured LOSS on QKV (R7).
template <typename OutT, bool HAS_BIAS, int BN>
__global__ __launch_bounds__(256, 4) void gemm_fw(const f16* __restrict__ A,
                                                  const float* __restrict__ W,
                                                  const float* __restrict__ scale,
                                                  const float* __restrict__ bias,
                                                  OutT* __restrict__ C,
                                                  int M, int N, int K) {
  constexpr int WN = BN / 2;
  constexpr int NF = WN / 16;
  constexpr int WCH = BN / 16;
  __shared__ alignas(16) f16 As[3][128 * 32];
  __shared__ alignas(16) f16 Ws[3][BN * 32];
  const int tid = threadIdx.x;
  const int lane = tid & 63;
  const int wid = tid >> 6;
  const int wm = wid >> 1, wn = wid & 1;
  const int bm = blockIdx.y * 128, bn = blockIdx.x * BN;

  const int fr = lane & 15;
  const int hi = lane >> 4;
  const int sw = (hi ^ ((fr >> 1) & 3)) * 8;

  const int c0 = wid, c1 = wid + 4;
  const int srow = lane >> 2;
  const int l4 = lane & 3;
  const int dcol = (l4 ^ ((srow >> 1) & 3)) * 8;
  const bool hasW1 = (c1 < WCH);

  const size_t arow0 = (size_t)(bm + c0 * 16 + srow) * K + l4 * 8;
  const size_t arow1 = (size_t)(bm + c1 * 16 + srow) * K + l4 * 8;
  const size_t wrow0 = (size_t)(bn + c0 * 16 + srow) * K + l4 * 8;
  const size_t wrow1 = (size_t)(bn + c1 * 16 + srow) * K + l4 * 8;

  f16x8 sa16[2];
  f32x4 swr[4];

  auto ISSUE = [&](int s) {
    const int kf = s << 5;
    sa16[0] = *(const f16x8*)(A + arow0 + kf);
    sa16[1] = *(const f16x8*)(A + arow1 + kf);
    const float* q0 = W + wrow0 + kf;
    swr[0] = *(const f32x4*)q0;
    swr[1] = *(const f32x4*)(q0 + 4);
    if (hasW1) {
      const float* q1 = W + wrow1 + kf;
      swr[2] = *(const f32x4*)q1;
      swr[3] = *(const f32x4*)(q1 + 4);
    }
  };

  auto CVT = [](f32x4 lo, f32x4 hiv) {
    f16x8 o;
    o[0] = (f16)lo[0]; o[1] = (f16)lo[1]; o[2] = (f16)lo[2]; o[3] = (f16)lo[3];
    o[4] = (f16)hiv[0]; o[5] = (f16)hiv[1]; o[6] = (f16)hiv[2]; o[7] = (f16)hiv[3];
    return o;
  };

  auto WRITE = [&](int buf) {
    *(f16x8*)(As[buf] + c0 * 512 + srow * 32 + dcol) = sa16[0];
    *(f16x8*)(As[buf] + c1 * 512 + srow * 32 + dcol) = sa16[1];
    *(f16x8*)(Ws[buf] + c0 * 512 + srow * 32 + dcol) = CVT(swr[0], swr[1]);
    if (hasW1)
      *(f16x8*)(Ws[buf] + c1 * 512 + srow * 32 + dcol) = CVT(swr[2], swr[3]);
  };

  f32x4 acc[4][NF] = {};

  const int nsteps = K >> 5;
  ISSUE(0);
  WRITE(0);
  ISSUE(1);

  int cur = 0;
  for (int s = 0; s < nsteps; ++s) {
    int nb = cur + 1;
    if (nb >= 3) nb -= 3;
    if (s + 1 < nsteps) WRITE(nb);
    if (s + 2 < nsteps) ISSUE(s + 2);
    asm volatile("s_waitcnt lgkmcnt(0)" ::: "memory");
    __builtin_amdgcn_s_barrier();
    asm volatile("" ::: "memory");

    f16x8 af[4], wf[NF];
#pragma unroll
    for (int i = 0; i < 4; ++i)
      af[i] = *(const f16x8*)(As[cur] + (wm * 64 + i * 16 + fr) * 32 + sw);
#pragma unroll
    for (int i = 0; i < NF; ++i)
      wf[i] = *(const f16x8*)(Ws[cur] + (wn * WN + i * 16 + fr) * 32 + sw);
#pragma unroll
    for (int mi = 0; mi < 4; ++mi)
#pragma unroll
      for (int ni = 0; ni < NF; ++ni)
        acc[mi][ni] = __builtin_amdgcn_mfma_f32_16x16x32_f16(af[mi], wf[ni], acc[mi][ni], 0, 0, 0);

    cur = nb;
  }

  const int rb = (lane >> 4) * 4;
#pragma unroll
  for (int ni = 0; ni < NF; ++ni) {
    int c = bn + wn * WN + ni * 16 + fr;
    float sc = scale[c];
    float bi = HAS_BIAS ? bias[c] : 0.0f;
#pragma unroll
    for (int mi = 0; mi < 4; ++mi) {
#pragma unroll
      for (int j = 0; j < 4; ++j) {
        int r = bm + wm * 64 + mi * 16 + rb + j;
        float v = acc[mi][ni][j] * sc + bi;
        C[(size_t)r * N + c] = (OutT)v;
      }
    }
  }
}

// ---------------- fused RoPE + V-transpose (one dispatch, R8 proven) ---------
__global__ __launch_bounds__(256) void rope_vt_kernel(const int* __restrict__ positions,
                                                      const f16* __restrict__ qkv,
                                                      f16* __restrict__ qkv_r,
                                                      f16* __restrict__ vt) {
  const int bid = blockIdx.x;
  if (bid < T_TOK) {
    int t = bid;
    float pos = (float)positions[t];
    const f16* in = qkv + (size_t)t * QKVN;
    f16* out = qkv_r + (size_t)t * QKVN;
#pragma unroll
    for (int it = 0; it < 8; ++it) {
      int item = it * 256 + threadIdx.x;
      int head = item >> 6;
      int j = item & 63;
      int col = (head < NQH) ? head * 128 : 3584 + (head - NQH) * 128;
      float freq = pos * exp2f(-(float)j * (19.931568569324174f / 64.0f));
      float s, c;
      sincosf(freq, &s, &c);
      float x1 = (float)in[col + j];
      float x2 = (float)in[col + j + 64];
      out[col + j] = (f16)(x1 * c - x2 * s);
      out[col + j + 64] = (f16)(x2 * c + x1 * s);
    }
  } else {
    int v = bid - T_TOK;
    int kv = v >> 6;
    int t0 = (v & 63) * 32;
    __shared__ f16 buf[32][136];
    const f16* src = qkv + 4096 + kv * 128;
#pragma unroll
    for (int it = 0; it < 16; ++it) {
      int e = it * 256 + threadIdx.x;
      int tt = e >> 7, d = e & 127;
      buf[tt][d] = src[(size_t)(t0 + tt) * QKVN + d];
    }
    __syncthreads();
#pragma unroll
    for (int it = 0; it < 16; ++it) {
      int e = it * 256 + threadIdx.x;
      int d = e >> 5, tt = e & 31;
      vt[((size_t)kv * 128 + d) * T_TOK + t0 + tt] = buf[tt][d];
    }
  }
}

// ---------------- Flash attention v8 (R8 proven): LDS-staged K AND V ---------
// R9 lesson: Vs staging IS the coalescing mechanism. vt is [d][t]; fragment
// reads need per-lane d -> 4KB lane stride if read direct from global (64
// cache lines per instruction, 222us). Staging reads V in 64B-contiguous
// chunks and the swizzled LDS read delivers fragments conflict-cheap.
__global__ __launch_bounds__(256, 2) void attn_kernel(const f16* __restrict__ qkv_r,
                                                      const f16* __restrict__ vt,
                                                      f16* __restrict__ o) {
  __shared__ alignas(16) f16 Ks[2][8192];
  __shared__ alignas(16) f16 Vs[2][8192];
  const int h = blockIdx.y;
  const int kv = h / 7;
  const int bq = blockIdx.x;               // 0..15
  const int tt = threadIdx.x;
  const int w = tt >> 6;
  const int lane = tt & 63;
  const int qa = 64 * bq + 16 * w;
  const int qb = 1984 - 64 * bq + 16 * w;
  const int fr = lane & 15;
  const int hi = lane >> 4;
  const int fk = hi * 8;
  const int rb = hi * 4;
  const int ntiles = 32 - bq;

  const f16* kgbase = qkv_r + 3584 + kv * 128;
  const f16* vgbase = vt + (size_t)kv * 128 * T_TOK;

  const int krow0 = tt >> 4, kc = tt & 15;
  const int vrow0 = tt >> 3, vc = tt & 7;
  const int kds = (kc ^ (krow0 & 7)) * 8;
  const int vds = (vc ^ (vrow0 & 7)) * 8;

  f16x8 qf[2][4];
#pragma unroll
  for (int fa = 0; fa < 2; ++fa) {
    const f16* qp = qkv_r + (size_t)((fa ? qb : qa) + fr) * QKVN + h * 128 + fk;
#pragma unroll
    for (int f = 0; f < 4; ++f) qf[fa][f] = *(const f16x8*)(qp + f * 32);
  }

  f32x4 oacc[2][8] = {};
  float m[2] = {-3.0e38f, -3.0e38f};
  float l[2] = {0.0f, 0.0f};

#pragma unroll
  for (int i = 0; i < 4; ++i) {
    f16x8 kx = *(const f16x8*)(kgbase + (size_t)(krow0 + 16 * i) * QKVN + kc * 8);
    f16x8 vx = *(const f16x8*)(vgbase + (size_t)(vrow0 + 32 * i) * T_TOK + vc * 8);
    *(f16x8*)&Ks[0][(krow0 + 16 * i) * 128 + kds] = kx;
    *(f16x8*)&Vs[0][(vrow0 + 32 * i) * 64 + vds] = vx;
  }
  __syncthreads();

  for (int tile = 0; tile < ntiles; ++tile) {
    const int s0 = tile << 6;
    const int cur = tile & 1;
    const bool havestage = (tile + 1 < ntiles);

    f16x8 sk[4], sv[4];
    if (havestage) {
      const int s1 = s0 + 64;
#pragma unroll
      for (int i = 0; i < 4; ++i) {
        sk[i] = *(const f16x8*)(kgbase + (size_t)(s1 + krow0 + 16 * i) * QKVN + kc * 8);
        sv[i] = *(const f16x8*)(vgbase + (size_t)(vrow0 + 32 * i) * T_TOK + s1 + vc * 8);
      }
    }

    {
      const f16* Kc = Ks[cur];
      const f16* Vc = Vs[cur];
      const bool actA = s0 < qa + 16;

      f32x4 sacc[2][4] = {};
      __builtin_amdgcn_s_setprio(1);
      if (actA) {
#pragma unroll
        for (int jj = 0; jj < 4; ++jj) {
          const int krow = jj * 16 + fr;
#pragma unroll
          for (int f = 0; f < 4; ++f) {
            f16x8 kf = *(const f16x8*)&Kc[krow * 128 + (((4 * f + hi) ^ (fr & 7)) * 8)];
            sacc[1][jj] = __builtin_amdgcn_mfma_f32_16x16x32_f16(kf, qf[1][f], sacc[1][jj], 0, 0, 0);
            sacc[0][jj] = __builtin_amdgcn_mfma_f32_16x16x32_f16(kf, qf[0][f], sacc[0][jj], 0, 0, 0);
          }
        }
      } else {
#pragma unroll
        for (int jj = 0; jj < 4; ++jj) {
          const int krow = jj * 16 + fr;
#pragma unroll
          for (int f = 0; f < 4; ++f) {
            f16x8 kf = *(const f16x8*)&Kc[krow * 128 + (((4 * f + hi) ^ (fr & 7)) * 8)];
            sacc[1][jj] = __builtin_amdgcn_mfma_f32_16x16x32_f16(kf, qf[1][f], sacc[1][jj], 0, 0, 0);
          }
        }
      }
      __builtin_amdgcn_s_setprio(0);

      int pw[2][2][4];
#pragma unroll
      for (int fa = 0; fa < 2; ++fa) {
        if (fa == 0 && !actA) continue;
        const int qrow = (fa ? qb : qa) + fr;
        float p[4][4];
#pragma unroll
        for (int jj = 0; jj < 4; ++jj)
#pragma unroll
          for (int jv = 0; jv < 4; ++jv) {
            int kvi = s0 + jj * 16 + rb + jv;
            float sv2 = sacc[fa][jj][jv] * SOFTMAX_SCALE;
            p[jj][jv] = (kvi <= qrow) ? sv2 : -3.0e38f;
          }
        float vmax = -3.0e38f;
#pragma unroll
        for (int jj = 0; jj < 4; ++jj)
          vmax = fmaxf(vmax, fmaxf(fmaxf(p[jj][0], p[jj][1]), fmaxf(p[jj][2], p[jj][3])));
        vmax = fmaxf(vmax, __shfl_xor(vmax, 16));
        vmax = fmaxf(vmax, __shfl_xor(vmax, 32));
        if (!__all(vmax <= m[fa] + 8.0f)) {
          float mn = fmaxf(m[fa], vmax);
          float corr = __expf(m[fa] - mn);
          m[fa] = mn;
          l[fa] *= corr;
#pragma unroll
          for (int jv = 0; jv < 4; ++jv) {
            float cj = __shfl(corr, rb + jv);
#pragma unroll
            for (int nd = 0; nd < 8; ++nd) oacc[fa][nd][jv] *= cj;
          }
        }
        float rs = 0.0f;
#pragma unroll
        for (int jj = 0; jj < 4; ++jj)
#pragma unroll
          for (int jv = 0; jv < 4; ++jv) {
            p[jj][jv] = __expf(p[jj][jv] - m[fa]);
            rs += p[jj][jv];
          }
        rs += __shfl_xor(rs, 16);
        rs += __shfl_xor(rs, 32);
        l[fa] += rs;

        int wp[4][2];
#pragma unroll
        for (int jj = 0; jj < 4; ++jj)
#pragma unroll
          for (int u = 0; u < 2; ++u) {
            fp16x2 h2 = __builtin_amdgcn_cvt_pkrtz(p[jj][2 * u], p[jj][2 * u + 1]);
            wp[jj][u] = __builtin_bit_cast(int, h2);
          }
#pragma unroll
        for (int c = 0; c < 2; ++c)
#pragma unroll
          for (int t = 0; t < 4; ++t) {
            int src = fr + 16 * (2 * (hi & 1) + (t >> 1));
            int a0 = __shfl(wp[2 * c][t & 1], src);
            int b0 = __shfl(wp[2 * c + 1][t & 1], src);
            pw[fa][c][t] = (hi >> 1) ? b0 : a0;
          }
      }

      __builtin_amdgcn_s_setprio(1);
#pragma unroll
      for (int c = 0; c < 2; ++c) {
        i32x4 t1 = {pw[1][c][0], pw[1][c][1], pw[1][c][2], pw[1][c][3]};
        f16x8 pf1 = __builtin_bit_cast(f16x8, t1);
        if (actA) {
          i32x4 t0 = {pw[0][c][0], pw[0][c][1], pw[0][c][2], pw[0][c][3]};
          f16x8 pf0 = __builtin_bit_cast(f16x8, t0);
#pragma unroll
          for (int nd = 0; nd < 8; ++nd) {
            f16x8 vf = *(const f16x8*)&Vc[(nd * 16 + fr) * 64 + (((4 * c + hi) ^ (fr & 7)) * 8)];
            oacc[1][nd] = __builtin_amdgcn_mfma_f32_16x16x32_f16(pf1, vf, oacc[1][nd], 0, 0, 0);
            oacc[0][nd] = __builtin_amdgcn_mfma_f32_16x16x32_f16(pf0, vf, oacc[0][nd], 0, 0, 0);
          }
        } else {
#pragma unroll
          for (int nd = 0; nd < 8; ++nd) {
            f16x8 vf = *(const f16x8*)&Vc[(nd * 16 + fr) * 64 + (((4 * c + hi) ^ (fr & 7)) * 8)];
            oacc[1][nd] = __builtin_amdgcn_mfma_f32_16x16x32_f16(pf1, vf, oacc[1][nd], 0, 0, 0);
          }
        }
      }
      __builtin_amdgcn_s_setprio(0);
    }

    if (havestage) {
      const int nxt = cur ^ 1;
#pragma unroll
      for (int i = 0; i < 4; ++i) {
        *(f16x8*)&Ks[nxt][(krow0 + 16 * i) * 128 + kds] = sk[i];
        *(f16x8*)&Vs[nxt][(vrow0 + 32 * i) * 64 + vds] = sv[i];
      }
      __syncthreads();
    }
  }

#pragma unroll
  for (int fa = 0; fa < 2; ++fa) {
    float inv[4];
#pragma unroll
    for (int jv = 0; jv < 4; ++jv) inv[jv] = 1.0f / __shfl(l[fa], rb + jv);
    f16* ob = o + (size_t)(fa ? qb : qa) * OROW + h * 128;
#pragma unroll
    for (int nd = 0; nd < 8; ++nd)
#pragma unroll
      for (int jv = 0; jv < 4; ++jv)
        ob[(size_t)(rb + jv) * OROW + nd * 16 + fr] = (f16)(oacc[fa][nd][jv] * inv[jv]);
  }
}

extern "C" void kernel_launch(void* const* d_in, const int* in_sizes, int n_in,
                              void* d_out, int out_size, void* d_ws, size_t ws_size,
                              hipStream_t stream) {
  (void)in_sizes; (void)n_in; (void)out_size; (void)ws_size;
  const int* positions = (const int*)d_in[0];
  const float* hidden = (const float*)d_in[1];
  const float* qkv_w = (const float*)d_in[2];
  const float* qkv_scale = (const float*)d_in[3];
  const float* qkv_bias = (const float*)d_in[4];
  const float* o_w = (const float*)d_in[5];
  const float* o_scale = (const float*)d_in[6];
  float* out = (float*)d_out;

  char* ws = (char*)d_ws;
  size_t off = 0;
  auto alloc = [&](size_t bytes) {
    char* p = ws + off;
    off += (bytes + 255) & ~(size_t)255;
    return p;
  };
  f16* bufA = (f16*)alloc((size_t)T_TOK * HD * 2);   // hidden f16, later attn out
  f16* bufB = (f16*)alloc((size_t)QKVN * HD * 2);    // qkv_w f16
  f16* qkv_h = (f16*)alloc((size_t)T_TOK * QKVN * 2);
  f16* qkv_r = (f16*)alloc((size_t)T_TOK * QKVN * 2);
  f16* vtb = (f16*)alloc((size_t)NKVH * 128 * T_TOK * 2);

  // one dispatch: hidden + qkv_w f32->f16
  const int n1 = T_TOK * HD, n2 = QKVN * HD;
  cvt2_kernel<<<(n1 + n2) / 2048, 256, 0, stream>>>(hidden, bufA, n1, qkv_w, bufB, n2);

  // QKV GEMM: proven gload_lds path, 96-col tiles -> 768 blocks = 3.0/CU
  gemm_lds<f16, true, 96><<<dim3(QKVN / 96, T_TOK / 128), 256, 0, stream>>>(
      bufA, bufB, qkv_scale, qkv_bias, qkv_h, T_TOK, QKVN, HD);

  // one dispatch: rope (blocks 0..2047) + V-transpose (blocks 2048..2303)
  rope_vt_kernel<<<T_TOK + (T_TOK / 32) * NKVH, 256, 0, stream>>>(
      positions, qkv_h, qkv_r, vtb);

  attn_kernel<<<dim3(16, NQH), 256, 0, stream>>>(qkv_r, vtb, bufA);

  // O GEMM: fused-W reg-staging (R4/R5 winner): A = attn out f16, W = o_w f32.
  gemm_fw<float, false, 128><<<dim3(OROW / 128, T_TOK / 128), 256, 0, stream>>>(
      bufA, o_w, o_scale, nullptr, out, T_TOK, OROW, HD);
}